// Round 1
// baseline (16223.747 us; speedup 1.0000x reference)
//
#include <hip/hip_runtime.h>

// Problem constants (fixed by the reference): T=512, B=64, I=256, H=512.
#define T_DIM 512
#define B_DIM 64
#define I_DIM 256
#define H_DIM 512
#define BH_DIM (B_DIM * H_DIM)   // 32768

// ---------------------------------------------------------------------------
// Stage 1: xw[t,b,h] = dot(x[t,b,:], Wih[h,:]) + bias_ih[h] + bias_hh[h]
// GEMM, M = T*B = 32768, N = H = 512, K = I = 256. Both operands K-major (NT).
// Tiling: BM=64, BN=64, BK=32. 256 threads, 4x4 register tile per thread.
// LDS staged transposed ([k][m] / [k][n]) so compute reads are float4.
// ---------------------------------------------------------------------------
__global__ __launch_bounds__(256) void xw_gemm(
    const float* __restrict__ x, const float* __restrict__ wih,
    const float* __restrict__ bih, const float* __restrict__ bhh,
    float* __restrict__ out) {
  // pad row to 68 floats: keeps rows 16B-aligned, breaks power-of-2 banks
  __shared__ float xs[32][68];  // [k][m]
  __shared__ float ws[32][68];  // [k][n]

  const int m_base = blockIdx.y * 64;
  const int n_base = blockIdx.x * 64;
  const int tid = threadIdx.x;
  const int tn = tid & 15;         // n-group 0..15
  const int tm = tid >> 4;         // m-group 0..15
  const int lr = tid >> 3;         // staging row 0..31
  const int lk = (tid & 7) << 2;   // staging k offset 0,4,...,28

  float acc[4][4];
#pragma unroll
  for (int i = 0; i < 4; i++)
#pragma unroll
    for (int j = 0; j < 4; j++) acc[i][j] = 0.f;

  for (int kc = 0; kc < I_DIM; kc += 32) {
    __syncthreads();
    // stage x tile (64 m x 32 k) and w tile (64 n x 32 k), transposing into LDS
    const float4 xv0 = *(const float4*)&x[(size_t)(m_base + lr) * I_DIM + kc + lk];
    const float4 xv1 = *(const float4*)&x[(size_t)(m_base + lr + 32) * I_DIM + kc + lk];
    const float4 wv0 = *(const float4*)&wih[(size_t)(n_base + lr) * I_DIM + kc + lk];
    const float4 wv1 = *(const float4*)&wih[(size_t)(n_base + lr + 32) * I_DIM + kc + lk];
    xs[lk + 0][lr] = xv0.x; xs[lk + 1][lr] = xv0.y;
    xs[lk + 2][lr] = xv0.z; xs[lk + 3][lr] = xv0.w;
    xs[lk + 0][lr + 32] = xv1.x; xs[lk + 1][lr + 32] = xv1.y;
    xs[lk + 2][lr + 32] = xv1.z; xs[lk + 3][lr + 32] = xv1.w;
    ws[lk + 0][lr] = wv0.x; ws[lk + 1][lr] = wv0.y;
    ws[lk + 2][lr] = wv0.z; ws[lk + 3][lr] = wv0.w;
    ws[lk + 0][lr + 32] = wv1.x; ws[lk + 1][lr + 32] = wv1.y;
    ws[lk + 2][lr + 32] = wv1.z; ws[lk + 3][lr + 32] = wv1.w;
    __syncthreads();

#pragma unroll
    for (int k = 0; k < 32; k++) {
      const float4 a = *(const float4*)&xs[k][tm * 4];
      const float4 b = *(const float4*)&ws[k][tn * 4];
      acc[0][0] = fmaf(a.x, b.x, acc[0][0]); acc[0][1] = fmaf(a.x, b.y, acc[0][1]);
      acc[0][2] = fmaf(a.x, b.z, acc[0][2]); acc[0][3] = fmaf(a.x, b.w, acc[0][3]);
      acc[1][0] = fmaf(a.y, b.x, acc[1][0]); acc[1][1] = fmaf(a.y, b.y, acc[1][1]);
      acc[1][2] = fmaf(a.y, b.z, acc[1][2]); acc[1][3] = fmaf(a.y, b.w, acc[1][3]);
      acc[2][0] = fmaf(a.z, b.x, acc[2][0]); acc[2][1] = fmaf(a.z, b.y, acc[2][1]);
      acc[2][2] = fmaf(a.z, b.z, acc[2][2]); acc[2][3] = fmaf(a.z, b.w, acc[2][3]);
      acc[3][0] = fmaf(a.w, b.x, acc[3][0]); acc[3][1] = fmaf(a.w, b.y, acc[3][1]);
      acc[3][2] = fmaf(a.w, b.z, acc[3][2]); acc[3][3] = fmaf(a.w, b.w, acc[3][3]);
    }
  }

  // epilogue: add (bias_ih + bias_hh), store coalesced float4 along n
  const int n0 = n_base + tn * 4;
  float4 bias;
  bias.x = bih[n0 + 0] + bhh[n0 + 0];
  bias.y = bih[n0 + 1] + bhh[n0 + 1];
  bias.z = bih[n0 + 2] + bhh[n0 + 2];
  bias.w = bih[n0 + 3] + bhh[n0 + 3];
#pragma unroll
  for (int mi = 0; mi < 4; mi++) {
    const int m = m_base + tm * 4 + mi;
    float4 o;
    o.x = acc[mi][0] + bias.x; o.y = acc[mi][1] + bias.y;
    o.z = acc[mi][2] + bias.z; o.w = acc[mi][3] + bias.w;
    *(float4*)&out[(size_t)m * H_DIM + n0] = o;
  }
}

// ---------------------------------------------------------------------------
// Stage 2: sequential scan. One block per batch element b (64 blocks) -- the
// recurrences are independent across b, so NO cross-block sync is needed.
// h_t lives in d_out[t] (in-place over xw_t, which is exactly output[t]).
// 256 threads; thread owns rows j and j+256 of W_hh. W_hh streams from L2
// each step (1 MB/block/step) -- known L2-bound baseline, to be replaced by
// LDS-resident split-bf16 MFMA in a later round.
// ---------------------------------------------------------------------------
__global__ __launch_bounds__(256) void rnn_scan(
    const float* __restrict__ whh, float* __restrict__ out) {
  const int b = blockIdx.x;
  const int tid = threadIdx.x;
  const int j0 = tid;
  const int j1 = tid + 256;
  const float4* __restrict__ w0 = (const float4*)(whh + (size_t)j0 * H_DIM);
  const float4* __restrict__ w1 = (const float4*)(whh + (size_t)j1 * H_DIM);

  float h0, h1;
  // t = 0: h = relu(xw_0)
  {
    float* o = out + (size_t)b * H_DIM;
    h0 = fmaxf(o[j0], 0.f);
    h1 = fmaxf(o[j1], 0.f);
    o[j0] = h0;
    o[j1] = h1;
  }

  for (int t = 1; t < T_DIM; t++) {
    // make previous step's global writes visible to the whole block
    __threadfence_block();
    __syncthreads();
    const float4* __restrict__ hp =
        (const float4*)(out + (size_t)(t - 1) * BH_DIM + (size_t)b * H_DIM);
    float* o = out + (size_t)t * BH_DIM + (size_t)b * H_DIM;
    float acc0 = o[j0];
    float acc1 = o[j1];
#pragma unroll 4
    for (int k4 = 0; k4 < H_DIM / 4; k4++) {
      const float4 hv = hp[k4];  // same addr across wave -> L1 broadcast
      const float4 a = w0[k4];
      const float4 c = w1[k4];
      acc0 = fmaf(a.x, hv.x, acc0); acc0 = fmaf(a.y, hv.y, acc0);
      acc0 = fmaf(a.z, hv.z, acc0); acc0 = fmaf(a.w, hv.w, acc0);
      acc1 = fmaf(c.x, hv.x, acc1); acc1 = fmaf(c.y, hv.y, acc1);
      acc1 = fmaf(c.z, hv.z, acc1); acc1 = fmaf(c.w, hv.w, acc1);
    }
    h0 = fmaxf(acc0, 0.f);
    h1 = fmaxf(acc1, 0.f);
    o[j0] = h0;
    o[j1] = h1;
  }

  // h_final = h at t = T-1 (each thread owns its own values; no sync needed)
  float* fin = out + (size_t)T_DIM * BH_DIM + (size_t)b * H_DIM;
  fin[j0] = h0;
  fin[j1] = h1;
}

extern "C" void kernel_launch(void* const* d_in, const int* in_sizes, int n_in,
                              void* d_out, int out_size, void* d_ws, size_t ws_size,
                              hipStream_t stream) {
  const float* x   = (const float*)d_in[0];  // [T,B,I]
  const float* wih = (const float*)d_in[1];  // [H,I]
  const float* whh = (const float*)d_in[2];  // [H,H]
  const float* bih = (const float*)d_in[3];  // [H]
  const float* bhh = (const float*)d_in[4];  // [H]
  float* out = (float*)d_out;                // [T,B,H] output ++ [B,H] h_final

  // Stage 1: xw -> d_out[0 : T*B*H]
  dim3 g1(H_DIM / 64, (T_DIM * B_DIM) / 64);  // (8, 512) tiles
  xw_gemm<<<g1, 256, 0, stream>>>(x, wih, bih, bhh, out);

  // Stage 2: in-place scan over d_out, h_final appended
  rnn_scan<<<B_DIM, 256, 0, stream>>>(whh, out);
}

// Round 2
// 14539.619 us; speedup vs baseline: 1.1158x; 1.1158x over previous
//
#include <hip/hip_runtime.h>

// Problem constants (fixed by the reference): T=512, B=64, I=256, H=512.
#define T_DIM 512
#define B_DIM 64
#define I_DIM 256
#define H_DIM 512
#define BH_DIM (B_DIM * H_DIM)   // 32768

// ---------------------------------------------------------------------------
// Stage 1: xw[t,b,h] = dot(x[t,b,:], Wih[h,:]) + bias_ih[h] + bias_hh[h]
// GEMM, M = T*B = 32768, N = H = 512, K = I = 256 (NT). BM=BN=64, BK=32,
// 256 threads, 4x4 register tile. ~200us, 1% of round-1 total -- untouched.
// ---------------------------------------------------------------------------
__global__ __launch_bounds__(256) void xw_gemm(
    const float* __restrict__ x, const float* __restrict__ wih,
    const float* __restrict__ bih, const float* __restrict__ bhh,
    float* __restrict__ out) {
  __shared__ float xs[32][68];  // [k][m], padded row
  __shared__ float ws[32][68];  // [k][n]

  const int m_base = blockIdx.y * 64;
  const int n_base = blockIdx.x * 64;
  const int tid = threadIdx.x;
  const int tn = tid & 15;
  const int tm = tid >> 4;
  const int lr = tid >> 3;
  const int lk = (tid & 7) << 2;

  float acc[4][4];
#pragma unroll
  for (int i = 0; i < 4; i++)
#pragma unroll
    for (int j = 0; j < 4; j++) acc[i][j] = 0.f;

  for (int kc = 0; kc < I_DIM; kc += 32) {
    __syncthreads();
    const float4 xv0 = *(const float4*)&x[(size_t)(m_base + lr) * I_DIM + kc + lk];
    const float4 xv1 = *(const float4*)&x[(size_t)(m_base + lr + 32) * I_DIM + kc + lk];
    const float4 wv0 = *(const float4*)&wih[(size_t)(n_base + lr) * I_DIM + kc + lk];
    const float4 wv1 = *(const float4*)&wih[(size_t)(n_base + lr + 32) * I_DIM + kc + lk];
    xs[lk + 0][lr] = xv0.x; xs[lk + 1][lr] = xv0.y;
    xs[lk + 2][lr] = xv0.z; xs[lk + 3][lr] = xv0.w;
    xs[lk + 0][lr + 32] = xv1.x; xs[lk + 1][lr + 32] = xv1.y;
    xs[lk + 2][lr + 32] = xv1.z; xs[lk + 3][lr + 32] = xv1.w;
    ws[lk + 0][lr] = wv0.x; ws[lk + 1][lr] = wv0.y;
    ws[lk + 2][lr] = wv0.z; ws[lk + 3][lr] = wv0.w;
    ws[lk + 0][lr + 32] = wv1.x; ws[lk + 1][lr + 32] = wv1.y;
    ws[lk + 2][lr + 32] = wv1.z; ws[lk + 3][lr + 32] = wv1.w;
    __syncthreads();

#pragma unroll
    for (int k = 0; k < 32; k++) {
      const float4 a = *(const float4*)&xs[k][tm * 4];
      const float4 b = *(const float4*)&ws[k][tn * 4];
      acc[0][0] = fmaf(a.x, b.x, acc[0][0]); acc[0][1] = fmaf(a.x, b.y, acc[0][1]);
      acc[0][2] = fmaf(a.x, b.z, acc[0][2]); acc[0][3] = fmaf(a.x, b.w, acc[0][3]);
      acc[1][0] = fmaf(a.y, b.x, acc[1][0]); acc[1][1] = fmaf(a.y, b.y, acc[1][1]);
      acc[1][2] = fmaf(a.y, b.z, acc[1][2]); acc[1][3] = fmaf(a.y, b.w, acc[1][3]);
      acc[2][0] = fmaf(a.z, b.x, acc[2][0]); acc[2][1] = fmaf(a.z, b.y, acc[2][1]);
      acc[2][2] = fmaf(a.z, b.z, acc[2][2]); acc[2][3] = fmaf(a.z, b.w, acc[2][3]);
      acc[3][0] = fmaf(a.w, b.x, acc[3][0]); acc[3][1] = fmaf(a.w, b.y, acc[3][1]);
      acc[3][2] = fmaf(a.w, b.z, acc[3][2]); acc[3][3] = fmaf(a.w, b.w, acc[3][3]);
    }
  }

  const int n0 = n_base + tn * 4;
  float4 bias;
  bias.x = bih[n0 + 0] + bhh[n0 + 0];
  bias.y = bih[n0 + 1] + bhh[n0 + 1];
  bias.z = bih[n0 + 2] + bhh[n0 + 2];
  bias.w = bih[n0 + 3] + bhh[n0 + 3];
#pragma unroll
  for (int mi = 0; mi < 4; mi++) {
    const int m = m_base + tm * 4 + mi;
    float4 o;
    o.x = acc[mi][0] + bias.x; o.y = acc[mi][1] + bias.y;
    o.z = acc[mi][2] + bias.z; o.w = acc[mi][3] + bias.w;
    *(float4*)&out[(size_t)m * H_DIM + n0] = o;
  }
}

// ---------------------------------------------------------------------------
// Stage 2: sequential scan, one block per batch (no cross-block sync).
// Round-2 restructure: 1024 threads (16 waves/CU, 4/SIMD) for latency hiding.
// Thread (j, half) owns W_hh[j][half*256 .. half*256+255]: 64 float4 global
// loads/step (the 1 MB/CU/step W stream). h_prev lives in an LDS double
// buffer; each wave's LDS read instr touches only 2 distinct float4 addrs
// (even lanes kbase=0, odd kbase=256) -> broadcast, conflict-free.
// Halves combine with __shfl_xor(acc,1) (partners adjacent in same wave64).
// One __syncthreads per step (double buffer makes it sufficient).
// ---------------------------------------------------------------------------
__global__ __launch_bounds__(1024) void rnn_scan(
    const float* __restrict__ whh, float* __restrict__ out) {
  __shared__ __align__(16) float hbuf[2][H_DIM];

  const int b = blockIdx.x;
  const int tid = threadIdx.x;   // 0..1023
  const int j = tid >> 1;        // output row 0..511
  const int half = tid & 1;      // k-half 0/1
  const int kbase = half * 256;  // my 256-column chunk of row j

  const float4* __restrict__ wrow =
      (const float4*)(whh + (size_t)j * H_DIM + kbase);  // 64 float4
  float* __restrict__ outb = out + (size_t)b * H_DIM;    // t-stride = BH_DIM

  // t = 0: h = relu(xw_0)
  float h0 = fmaxf(outb[j], 0.f);  // pair lanes read same addr (coalesced)
  if (half == 0) {
    outb[j] = h0;
    hbuf[0][j] = h0;
  }
  __syncthreads();
  float hfin = h0;

  for (int t = 1; t < T_DIM; t++) {
    const float* __restrict__ hp = hbuf[(t - 1) & 1];
    float* __restrict__ o = outb + (size_t)t * BH_DIM;
    const float xw = o[j];  // prefetch xw_t[j] early to overlap latency

    float a0 = 0.f, a1 = 0.f, a2 = 0.f, a3 = 0.f;
#pragma unroll 8
    for (int k4 = 0; k4 < 64; k4++) {
      const float4 w = wrow[k4];
      const float4 hv = *(const float4*)&hp[kbase + k4 * 4];
      a0 = fmaf(w.x, hv.x, a0);
      a1 = fmaf(w.y, hv.y, a1);
      a2 = fmaf(w.z, hv.z, a2);
      a3 = fmaf(w.w, hv.w, a3);
    }
    float acc = (a0 + a1) + (a2 + a3);
    acc += __shfl_xor(acc, 1, 64);  // combine the two k-halves of row j

    const float hx = fmaxf(acc + xw, 0.f);
    if (half == 0) {
      o[j] = hx;            // output[t,b,j]
      hbuf[t & 1][j] = hx;  // h for next step
    }
    hfin = hx;
    __syncthreads();  // separates this step's LDS reads from next writes
  }

  // h_final = h_{T-1}
  if (half == 0) {
    out[(size_t)T_DIM * BH_DIM + (size_t)b * H_DIM + j] = hfin;
  }
}

extern "C" void kernel_launch(void* const* d_in, const int* in_sizes, int n_in,
                              void* d_out, int out_size, void* d_ws, size_t ws_size,
                              hipStream_t stream) {
  const float* x   = (const float*)d_in[0];  // [T,B,I]
  const float* wih = (const float*)d_in[1];  // [H,I]
  const float* whh = (const float*)d_in[2];  // [H,H]
  const float* bih = (const float*)d_in[3];  // [H]
  const float* bhh = (const float*)d_in[4];  // [H]
  float* out = (float*)d_out;                // [T,B,H] output ++ [B,H] h_final

  dim3 g1(H_DIM / 64, (T_DIM * B_DIM) / 64);  // (8, 512) tiles
  xw_gemm<<<g1, 256, 0, stream>>>(x, wih, bih, bhh, out);

  rnn_scan<<<B_DIM, 1024, 0, stream>>>(whh, out);
}